// Round 8
// baseline (3292.677 us; speedup 1.0000x reference)
//
#include <hip/hip_runtime.h>
#include <math.h>

#define Bb 256
#define Tt 512
#define Ii 128
#define Hh 256
#define Ss 4
#define G4 1024  // 4*H gate rows
#define TILE 8   // x-gate precompute tile

// Paired-batch recurrence: 128 blocks x 512 threads; each block runs TWO
// batches (sorted by length, adjacent pair) through the SAME weight stream.
// Per-thread W_hh row split: 18 chunks LDS-resident, 46 streamed from L2
// (shared by both batches -> per-batch L2 traffic halves; only 16 CUs/XCD
// active -> per-CU L2 share doubles). VGPR budget = 65536/512 = 128 (HW
// pins it; rounds 3-6 evidence) -> no VGPR-resident weights; regs hold
// xg[4][8], 4 accumulators, 13-deep streamed in-flight ladder.

typedef _Float16 half2t __attribute__((ext_vector_type(2)));
union W16 { uint4 u; half2t h[4]; };
union CV8 { _Float16 h[4]; uint2 u; };

__device__ __forceinline__ float dot8(uint4 w, uint4 hv, float acc) {
  W16 a; a.u = w; W16 b; b.u = hv;
#if __has_builtin(__builtin_amdgcn_fdot2)
  acc = __builtin_amdgcn_fdot2(a.h[0], b.h[0], acc, false);
  acc = __builtin_amdgcn_fdot2(a.h[1], b.h[1], acc, false);
  acc = __builtin_amdgcn_fdot2(a.h[2], b.h[2], acc, false);
  acc = __builtin_amdgcn_fdot2(a.h[3], b.h[3], acc, false);
#else
#pragma unroll
  for (int k = 0; k < 4; k++)
    acc += (float)a.h[k].x * (float)b.h[k].x + (float)a.h[k].y * (float)b.h[k].y;
#endif
  return acc;
}

__device__ __forceinline__ float sigf(float x) { return 1.f / (1.f + expf(-x)); }

// ---------------- kernel 1: lengths[b] = max(sum(mask[b,:]), 1) ----------------
__global__ void k_len(const int* __restrict__ mask, int* __restrict__ len) {
  int b = blockIdx.x, tid = threadIdx.x;
  int c = (mask[b * Tt + tid] != 0) + (mask[b * Tt + 256 + tid] != 0);
#pragma unroll
  for (int off = 32; off > 0; off >>= 1) c += __shfl_down(c, off, 64);
  __shared__ int red[4];
  if ((tid & 63) == 0) red[tid >> 6] = c;
  __syncthreads();
  if (tid == 0) {
    int t = red[0] + red[1] + red[2] + red[3];
    len[b] = t < 1 ? 1 : t;
  }
}

// ---------------- kernel 1b: perm = argsort(len) ascending (stable) ------------
__global__ void k_sort(const int* __restrict__ len, int* __restrict__ perm) {
  __shared__ int l[Bb];
  int tid = threadIdx.x;
  l[tid] = len[tid];
  __syncthreads();
  int me = l[tid], r = 0;
  for (int j = 0; j < Bb; j++) {
    int lj = l[j];
    r += (lj < me) || (lj == me && j < tid);
  }
  perm[r] = tid;
}

// ---------------- kernel 2: weight transforms (fp32 -> packed fp16) ------------
// wt_hh16[(s*32+i8)*1024+o] = 8 halfs {W_hh[s][o][8i8..8i8+7]}
// wt_ih16[(s*16+i8)*1024+o] = 8 halfs {W_ih[s][o][8i8..8i8+7]}
__global__ void k_tr(const float* __restrict__ W_ih, const float* __restrict__ W_hh,
                     uint4* __restrict__ wt_hh16, uint4* __restrict__ wt_ih16) {
  int id = blockIdx.x * blockDim.x + threadIdx.x;
  const int NH16 = Ss * 32 * G4;  // 131072
  const int NI16 = Ss * 16 * G4;  // 65536
  if (id < NH16) {
    int o = id % G4, i8 = (id / G4) % 32, s = id / (G4 * 32);
    const float* src = W_hh + ((size_t)(s * G4 + o)) * Hh + 8 * i8;
    W16 w;
#pragma unroll
    for (int k = 0; k < 4; k++) {
      w.h[k].x = (_Float16)src[2 * k];
      w.h[k].y = (_Float16)src[2 * k + 1];
    }
    wt_hh16[id] = w.u;
  } else if (id < NH16 + NI16) {
    int id3 = id - NH16;
    int o = id3 % G4, i8 = (id3 / G4) % 16, s = id3 / (G4 * 16);
    const float* src = W_ih + ((size_t)(s * G4 + o)) * Ii + 8 * i8;
    W16 w;
#pragma unroll
    for (int k = 0; k < 4; k++) {
      w.h[k].x = (_Float16)src[2 * k];
      w.h[k].y = (_Float16)src[2 * k + 1];
    }
    wt_ih16[id3] = w.u;
  }
}

// ---------------- kernel 3: paired fused recurrence ----------------------------
__global__ __launch_bounds__(512) void k_fused(
    const float* __restrict__ x, const uint4* __restrict__ wt_hh16,
    const uint4* __restrict__ wt_ih16, const float* __restrict__ b_ih,
    const float* __restrict__ b_hh, const int* __restrict__ len,
    const int* __restrict__ perm, float* __restrict__ out) {
  __shared__ __align__(16) uint4 lds_w[18 * 512];      // 144 KiB resident chunks
  __shared__ __align__(16) _Float16 xs[2][TILE * Ii];  // 4 KiB x tiles (fp16)
  __shared__ __align__(16) _Float16 h1_h[Hh], h2_h[Hh];
  __shared__ float fo_sh[2][2][Hh];  // [batch][f|o][u]
  const int g = blockIdx.x;
  const int tid = threadIdx.x;
  const int u = tid & 255;
  const int pr = tid >> 8;
  const int r0 = u + pr * 256;  // i-row (pr0) / f-row (pr1)
  const int r1 = r0 + 512;      // g-row (pr0) / o-row (pr1)
  const int b1 = perm[2 * g], b2 = perm[2 * g + 1];
  const int L1 = len[b1], L2v = len[b2];  // sorted: L1 <= L2v
  // segment boundaries: seg(t) = #{ceil(i*L/4) <= t}
  const int A1 = (L1 + 3) >> 2, A2 = (2 * L1 + 3) >> 2, A3 = (3 * L1 + 3) >> 2;
  const int C1 = (L2v + 3) >> 2, C2 = (2 * L2v + 3) >> 2, C3 = (3 * L2v + 3) >> 2;
  if (tid < 256) { h1_h[tid] = (_Float16)0.f; }
  else { h2_h[tid - 256] = (_Float16)0.f; }
  float c1 = 0.f, c2 = 0.f;
  float* out1 = out + (size_t)b1 * Tt * Hh;
  float* out2 = out + (size_t)b2 * Tt * Hh;
  float* last1 = out + (size_t)Bb * Tt * Hh + (size_t)b1 * Hh;
  float* last2 = out + (size_t)Bb * Tt * Hh + (size_t)b2 * Hh;
  const uint4* h4a = (const uint4*)h1_h;
  const uint4* h4b = (const uint4*)h2_h;
  const uint4* xs4a = (const uint4*)xs[0];
  const uint4* xs4b = (const uint4*)xs[1];
  int s_cur = -1;
  float xg0_1[TILE], xg1_1[TILE], xg0_2[TILE], xg1_2[TILE];

  for (int t0 = 0; t0 < L2v; t0 += TILE) {  // t0 mult of 8 <= 504: no x overrun
    // ---- stage x tiles for both batches -> fp16 LDS (one float4/thread) ----
    {
      int m = tid >> 8, f = tid & 255;
      const float* xb = x + ((size_t)(m ? b2 : b1) * Tt + t0) * Ii;
      float4 xf = ((const float4*)xb)[f];
      CV8 cv;
      cv.h[0] = (_Float16)xf.x;
      cv.h[1] = (_Float16)xf.y;
      cv.h[2] = (_Float16)xf.z;
      cv.h[3] = (_Float16)xf.w;
      ((uint2*)xs[m])[f] = cv.u;
    }
    __syncthreads();  // xs visible (also h inits before first step)

    // ---- phase A, batch 1 (skip when tile entirely past L1) ----
    if (t0 < L1) {
      int s_lo = (t0 >= A1) + (t0 >= A2) + (t0 >= A3);
      int te = t0 + TILE - 1;
      int s_hi = (te >= A1) + (te >= A2) + (te >= A3);
      for (int s = s_lo; s <= s_hi; s++) {  // <= 2 iters (segment len >= 64)
        float acc0[TILE], acc1[TILE];
#pragma unroll
        for (int tt = 0; tt < TILE; tt++) { acc0[tt] = 0.f; acc1[tt] = 0.f; }
        const uint4* wbi = wt_ih16 + ((size_t)s * 16) * G4;
#pragma unroll 2
        for (int i8 = 0; i8 < 16; i8++) {
          uint4 w0 = wbi[(size_t)i8 * G4 + r0];
          uint4 w1 = wbi[(size_t)i8 * G4 + r1];
#pragma unroll
          for (int tt = 0; tt < TILE; tt++) {
            uint4 hv = xs4a[tt * 16 + i8];
            acc0[tt] = dot8(w0, hv, acc0[tt]);
            acc1[tt] = dot8(w1, hv, acc1[tt]);
          }
        }
        float bias0 = b_ih[s * G4 + r0] + b_hh[s * G4 + r0];
        float bias1 = b_ih[s * G4 + r1] + b_hh[s * G4 + r1];
#pragma unroll
        for (int tt = 0; tt < TILE; tt++) {
          int t = t0 + tt;
          int sg = (t >= A1) + (t >= A2) + (t >= A3);
          if (sg == s) { xg0_1[tt] = acc0[tt] + bias0; xg1_1[tt] = acc1[tt] + bias1; }
        }
      }
    }
    // ---- phase A, batch 2 ----
    {
      int s_lo = (t0 >= C1) + (t0 >= C2) + (t0 >= C3);
      int te = t0 + TILE - 1;
      int s_hi = (te >= C1) + (te >= C2) + (te >= C3);
      for (int s = s_lo; s <= s_hi; s++) {
        float acc0[TILE], acc1[TILE];
#pragma unroll
        for (int tt = 0; tt < TILE; tt++) { acc0[tt] = 0.f; acc1[tt] = 0.f; }
        const uint4* wbi = wt_ih16 + ((size_t)s * 16) * G4;
#pragma unroll 2
        for (int i8 = 0; i8 < 16; i8++) {
          uint4 w0 = wbi[(size_t)i8 * G4 + r0];
          uint4 w1 = wbi[(size_t)i8 * G4 + r1];
#pragma unroll
          for (int tt = 0; tt < TILE; tt++) {
            uint4 hv = xs4b[tt * 16 + i8];
            acc0[tt] = dot8(w0, hv, acc0[tt]);
            acc1[tt] = dot8(w1, hv, acc1[tt]);
          }
        }
        float bias0 = b_ih[s * G4 + r0] + b_hh[s * G4 + r0];
        float bias1 = b_ih[s * G4 + r1] + b_hh[s * G4 + r1];
#pragma unroll
        for (int tt = 0; tt < TILE; tt++) {
          int t = t0 + tt;
          int sg = (t >= C1) + (t >= C2) + (t >= C3);
          if (sg == s) { xg0_2[tt] = acc0[tt] + bias0; xg1_2[tt] = acc1[tt] + bias1; }
        }
      }
    }

    // ---- recurrence steps ----
#pragma unroll
    for (int tt = 0; tt < TILE; tt++) {
      const int t = t0 + tt;
      if (t < L2v) {  // block-uniform
        int s2 = (t >= C1) + (t >= C2) + (t >= C3);
        int s1 = (t >= L1) ? s2 : (t >= A1) + (t >= A2) + (t >= A3);
        float a0_1 = xg0_1[tt], a1_1 = xg1_1[tt];
        float a0_2 = xg0_2[tt], a1_2 = xg1_2[tt];
        uint4 sA[22], sB[24];
        const uint4* wbs0;
        const uint4* wbs1;
        const bool fast = (s1 == s2);  // dynamically block-uniform
        if (fast) {
          if (s2 != s_cur) {  // block-uniform, <= 4 times
            s_cur = s2;
            const uint4* wb0 = wt_hh16 + (size_t)s2 * 32 * G4 + r0;
            const uint4* wb1 = wt_hh16 + (size_t)s2 * 32 * G4 + r1;
#pragma unroll
            for (int j = 0; j < 10; j++) lds_w[j * 512 + tid] = wb0[(size_t)j * G4];
#pragma unroll
            for (int j = 0; j < 8; j++)
              lds_w[(10 + j) * 512 + tid] = wb1[(size_t)j * G4];
          }
          wbs0 = wt_hh16 + (size_t)s_cur * 32 * G4 + r0;
          wbs1 = wt_hh16 + (size_t)s_cur * 32 * G4 + r1;
          // pre-barrier issues (complete during barrier wait)
          sB[0] = wbs1[(size_t)8 * G4];
          sB[1] = wbs1[(size_t)9 * G4];
          sA[0] = wbs0[(size_t)10 * G4];
          sA[1] = wbs0[(size_t)11 * G4];
        }
        __syncthreads();  // B1: prev h1_h/h2_h visible
        if (fast) {
          // sA[j] = r0 chunk 10+j (22); sB[j] = r1 chunk 8+j (24).
          // ladder: <=13 in flight, every load issued >=6 slots before use.
#pragma unroll
          for (int i8 = 0; i8 < 32; i8++) {
            if (i8 == 0) { sB[2] = wbs1[(size_t)10 * G4]; sA[2] = wbs0[(size_t)12 * G4]; }
            if (i8 == 1) { sB[3] = wbs1[(size_t)11 * G4]; sA[3] = wbs0[(size_t)13 * G4]; }
            if (i8 == 2) { sB[4] = wbs1[(size_t)12 * G4]; sA[4] = wbs0[(size_t)14 * G4]; }
            if (i8 == 3) { sB[5] = wbs1[(size_t)13 * G4]; sA[5] = wbs0[(size_t)15 * G4]; }
            if (i8 == 4) { sB[6] = wbs1[(size_t)14 * G4]; }
            if (i8 == 8) { sA[6] = wbs0[(size_t)16 * G4]; }
            if (i8 == 9) { sB[7] = wbs1[(size_t)15 * G4]; }
            if (i8 >= 10 && i8 <= 24) {
              sA[i8 - 3] = wbs0[(size_t)(i8 + 7) * G4];
              sB[i8 - 2] = wbs1[(size_t)(i8 + 6) * G4];
            }
            if (i8 == 25) { sB[23] = wbs1[(size_t)31 * G4]; }
            uint4 hv1 = h4a[i8];  // wave-uniform LDS broadcast
            uint4 hv2 = h4b[i8];
            uint4 wA = (i8 < 10) ? lds_w[i8 * 512 + tid] : sA[i8 - 10];
            uint4 wB = (i8 < 8) ? lds_w[(10 + i8) * 512 + tid] : sB[i8 - 8];
            a0_1 = dot8(wA, hv1, a0_1);
            a0_2 = dot8(wA, hv2, a0_2);
            a1_1 = dot8(wB, hv1, a1_1);
            a1_2 = dot8(wB, hv2, a1_2);
          }
        } else {
          // mismatch window (few steps/block): both batches fully streamed
          const uint4* p1 = wt_hh16 + (size_t)s1 * 32 * G4;
          const uint4* p2 = wt_hh16 + (size_t)s2 * 32 * G4;
#pragma unroll 2
          for (int i8 = 0; i8 < 32; i8++) {
            uint4 hv1 = h4a[i8], hv2 = h4b[i8];
            uint4 wA1 = p1[(size_t)i8 * G4 + r0], wB1 = p1[(size_t)i8 * G4 + r1];
            uint4 wA2 = p2[(size_t)i8 * G4 + r0], wB2 = p2[(size_t)i8 * G4 + r1];
            a0_1 = dot8(wA1, hv1, a0_1);
            a1_1 = dot8(wB1, hv1, a1_1);
            a0_2 = dot8(wA2, hv2, a0_2);
            a1_2 = dot8(wB2, hv2, a1_2);
          }
        }
        if (pr == 1) {  // f,o gates for both batches
          fo_sh[0][0][u] = sigf(a0_1);
          fo_sh[0][1][u] = sigf(a1_1);
          fo_sh[1][0][u] = sigf(a0_2);
          fo_sh[1][1][u] = sigf(a1_2);
        }
        __syncthreads();  // B2: h reads done; f/o visible
        if (pr == 0) {
          if (t < L1) {
            float ig = sigf(a0_1), gg = tanhf(a1_1);
            c1 = fo_sh[0][0][u] * c1 + ig * gg;
            float h = fo_sh[0][1][u] * tanhf(c1);
            h1_h[u] = (_Float16)h;
            out1[(size_t)t * Hh + u] = h;
            if (t == L1 - 1) last1[u] = h;
          }
          {
            float ig = sigf(a0_2), gg = tanhf(a1_2);
            c2 = fo_sh[1][0][u] * c2 + ig * gg;
            float h = fo_sh[1][1][u] * tanhf(c2);
            h2_h[u] = (_Float16)h;
            out2[(size_t)t * Hh + u] = h;
            if (t == L2v - 1) last2[u] = h;
          }
        }
      }
    }
  }
  // zero tails (coalesced float4, all 512 threads)
  {
    int z1 = (Tt - L1) * (Hh / 4);
    float4* zb = (float4*)(out1 + (size_t)L1 * Hh);
    float4 z; z.x = z.y = z.z = z.w = 0.f;
    for (int i = tid; i < z1; i += 512) zb[i] = z;
    int z2 = (Tt - L2v) * (Hh / 4);
    float4* zb2 = (float4*)(out2 + (size_t)L2v * Hh);
    for (int i = tid; i < z2; i += 512) zb2[i] = z;
  }
}

extern "C" void kernel_launch(void* const* d_in, const int* in_sizes, int n_in,
                              void* d_out, int out_size, void* d_ws, size_t ws_size,
                              hipStream_t stream) {
  const float* x = (const float*)d_in[0];
  const int* mask = (const int*)d_in[1];
  const float* W_ih = (const float*)d_in[2];
  const float* W_hh = (const float*)d_in[3];
  const float* b_ih = (const float*)d_in[4];
  const float* b_hh = (const float*)d_in[5];
  float* out = (float*)d_out;
  char* ws = (char*)d_ws;

  const size_t HH16_OFF = 0;
  const size_t HH16_BYTES = (size_t)Ss * 32 * G4 * 16;  // 2 MiB
  const size_t IH16_OFF = HH16_OFF + HH16_BYTES;
  const size_t IH16_BYTES = (size_t)Ss * 16 * G4 * 16;  // 1 MiB
  const size_t LEN_OFF = IH16_OFF + IH16_BYTES;
  const size_t PERM_OFF = LEN_OFF + 4096;

  uint4* wt_hh16 = (uint4*)(ws + HH16_OFF);
  uint4* wt_ih16 = (uint4*)(ws + IH16_OFF);
  int* len = (int*)(ws + LEN_OFF);
  int* perm = (int*)(ws + PERM_OFF);

  k_len<<<Bb, 256, 0, stream>>>(mask, len);
  k_sort<<<1, Bb, 0, stream>>>(len, perm);
  k_tr<<<768, 256, 0, stream>>>(W_ih, W_hh, wt_hh16, wt_ih16);
  k_fused<<<Bb / 2, 512, 0, stream>>>(x, wt_hh16, wt_ih16, b_ih, b_hh, len,
                                      perm, out);
}

// Round 9
// 2330.371 us; speedup vs baseline: 1.4129x; 1.4129x over previous
//
#include <hip/hip_runtime.h>
#include <math.h>

#define Bb 256
#define Tt 512
#define Ii 128
#define Hh 256
#define Ss 4
#define G4 1024  // 4*H gate rows
#define TILE 8   // x-gate precompute tile (xg in 16 fp32 regs)

// The gfx950 backend pins the per-thread VGPR budget to 65536/blockDim
// (512thr->128; rounds 3-6, no attribute overrides it) — but AGPRs are a
// SEPARATE allocatable class (unified file, MfmaUtil==0 so unused), reachable
// via inline-asm "a" constraints. W_hh residency per thread (2 rows x 32
// chunks of 16B):
//   r0: LDS c0..9  | w0v[6]=c10..15 | aA (AGPR) = c16..31  (16 chunks)
//   r1: LDS c0..8  | w1v[4]=c9..12  | aB (AGPR) = c13..31  (19 chunks)
// Steady-state step loop has ZERO global loads; weights (re)load only at <=4
// block-uniform segment transitions.

typedef _Float16 half2t __attribute__((ext_vector_type(2)));
union W16 { uint4 u; half2t h[4]; };
union CV8 { _Float16 h[4]; uint2 u; };

__device__ __forceinline__ float dot8(uint4 w, uint4 hv, float acc) {
  W16 a; a.u = w; W16 b; b.u = hv;
#if __has_builtin(__builtin_amdgcn_fdot2)
  acc = __builtin_amdgcn_fdot2(a.h[0], b.h[0], acc, false);
  acc = __builtin_amdgcn_fdot2(a.h[1], b.h[1], acc, false);
  acc = __builtin_amdgcn_fdot2(a.h[2], b.h[2], acc, false);
  acc = __builtin_amdgcn_fdot2(a.h[3], b.h[3], acc, false);
#else
#pragma unroll
  for (int k = 0; k < 4; k++)
    acc += (float)a.h[k].x * (float)b.h[k].x + (float)a.h[k].y * (float)b.h[k].y;
#endif
  return acc;
}

// AGPR stash helpers: "a"-constrained asm forces AGPR class; compiler tracks
// liveness and .agpr_count. All indices are compile-time constants (full unroll).
#define AGW4(a0_, a1_, a2_, a3_, src)                                        \
  do {                                                                        \
    asm volatile("v_accvgpr_write_b32 %0, %1" : "=a"(a0_) : "v"((src).x));   \
    asm volatile("v_accvgpr_write_b32 %0, %1" : "=a"(a1_) : "v"((src).y));   \
    asm volatile("v_accvgpr_write_b32 %0, %1" : "=a"(a2_) : "v"((src).z));   \
    asm volatile("v_accvgpr_write_b32 %0, %1" : "=a"(a3_) : "v"((src).w));   \
  } while (0)

#define AGR4(dst, a0_, a1_, a2_, a3_)                                        \
  do {                                                                        \
    asm volatile("v_accvgpr_read_b32 %0, %1" : "=v"((dst).x) : "a"(a0_));    \
    asm volatile("v_accvgpr_read_b32 %0, %1" : "=v"((dst).y) : "a"(a1_));    \
    asm volatile("v_accvgpr_read_b32 %0, %1" : "=v"((dst).z) : "a"(a2_));    \
    asm volatile("v_accvgpr_read_b32 %0, %1" : "=v"((dst).w) : "a"(a3_));    \
  } while (0)

// ---------------- kernel 1: lengths[b] = max(sum(mask[b,:]), 1) ----------------
__global__ void k_len(const int* __restrict__ mask, int* __restrict__ len) {
  int b = blockIdx.x, tid = threadIdx.x;
  int c = (mask[b * Tt + tid] != 0) + (mask[b * Tt + 256 + tid] != 0);
#pragma unroll
  for (int off = 32; off > 0; off >>= 1) c += __shfl_down(c, off, 64);
  __shared__ int red[4];
  if ((tid & 63) == 0) red[tid >> 6] = c;
  __syncthreads();
  if (tid == 0) {
    int t = red[0] + red[1] + red[2] + red[3];
    len[b] = t < 1 ? 1 : t;
  }
}

// ---------------- kernel 2: weight transforms (fp32 -> packed fp16) ------------
// wt_hh16[(s*32+i8)*1024+o] = 8 halfs {W_hh[s][o][8i8..8i8+7]}
// wt_ih16[(s*16+i8)*1024+o] = 8 halfs {W_ih[s][o][8i8..8i8+7]}
__global__ void k_tr(const float* __restrict__ W_ih, const float* __restrict__ W_hh,
                     uint4* __restrict__ wt_hh16, uint4* __restrict__ wt_ih16) {
  int id = blockIdx.x * blockDim.x + threadIdx.x;
  const int NH16 = Ss * 32 * G4;  // 131072
  const int NI16 = Ss * 16 * G4;  // 65536
  if (id < NH16) {
    int o = id % G4, i8 = (id / G4) % 32, s = id / (G4 * 32);
    const float* src = W_hh + ((size_t)(s * G4 + o)) * Hh + 8 * i8;
    W16 w;
#pragma unroll
    for (int k = 0; k < 4; k++) {
      w.h[k].x = (_Float16)src[2 * k];
      w.h[k].y = (_Float16)src[2 * k + 1];
    }
    wt_hh16[id] = w.u;
  } else if (id < NH16 + NI16) {
    int id3 = id - NH16;
    int o = id3 % G4, i8 = (id3 / G4) % 16, s = id3 / (G4 * 16);
    const float* src = W_ih + ((size_t)(s * G4 + o)) * Ii + 8 * i8;
    W16 w;
#pragma unroll
    for (int k = 0; k < 4; k++) {
      w.h[k].x = (_Float16)src[2 * k];
      w.h[k].y = (_Float16)src[2 * k + 1];
    }
    wt_ih16[id3] = w.u;
  }
}

// ---------------- kernel 3: fused recurrence, LDS+VGPR+AGPR-resident -----------
// 512 threads = 8 waves, 1 block/CU (156 KiB LDS). Thread (u=tid&255, pr=tid>>8)
// owns rows r0=u+pr*256 (i or f) and r1=r0+512 (g or o). pr=1 sends sigmoid(f),
// sigmoid(o) via LDS; pr=0 keeps c and writes h. Per TILE steps: stage x->fp16
// LDS, compute xg[2][TILE] with W_ih streamed once per tile. Per step: 64 hh
// dot8 = 19 LDS + 10 VGPR + 35 AGPR chunks — no global loads in steady state.
__global__ __launch_bounds__(512) void k_fused(
    const float* __restrict__ x, const uint4* __restrict__ wt_hh16,
    const uint4* __restrict__ wt_ih16, const float* __restrict__ b_ih,
    const float* __restrict__ b_hh, const int* __restrict__ len,
    float* __restrict__ out) {
  __shared__ __align__(16) uint4 lds_w[19 * 512];   // 152 KiB: L0..9=r0 c0..9, L10..18=r1 c0..8
  __shared__ __align__(16) _Float16 xs[TILE * Ii];  // 2 KiB x tile (fp16)
  __shared__ __align__(16) _Float16 h_h[Hh];        // 512 B
  __shared__ float f_sh[Hh];
  __shared__ float o_sh[Hh];
  const int b = blockIdx.x;
  const int tid = threadIdx.x;
  const int u = tid & 255;
  const int pr = tid >> 8;
  const int r0 = u + pr * 256;
  const int r1 = r0 + 512;
  const int L = len[b];
  // segment boundaries: seg(t) = #{tb_i <= t}, tb_i = ceil(i*L/4)
  const int tb1 = (L + 3) >> 2;
  const int tb2 = (2 * L + 3) >> 2;
  const int tb3 = (3 * L + 3) >> 2;
  if (pr == 0) h_h[u] = (_Float16)0.f;
  float c = 0.f;
  float* outb = out + (size_t)b * Tt * Hh;
  float* lastb = out + (size_t)Bb * Tt * Hh + (size_t)b * Hh;
  const uint4* h4 = (const uint4*)h_h;
  const uint4* xs4 = (const uint4*)xs;
  uint4 w0v[6];  // r0 chunks 10..15 (24 VGPRs)
  uint4 w1v[4];  // r1 chunks 9..12  (16 VGPRs)
  unsigned aA[64];  // AGPR: r0 chunks 16..31 (16 x 4)
  unsigned aB[76];  // AGPR: r1 chunks 13..31 (19 x 4)
  {  // zero-init AGPR stash (defined on all paths before any read)
    unsigned z = 0;
#pragma unroll
    for (int k = 0; k < 64; k++)
      asm volatile("v_accvgpr_write_b32 %0, %1" : "=a"(aA[k]) : "v"(z));
#pragma unroll
    for (int k = 0; k < 76; k++)
      asm volatile("v_accvgpr_write_b32 %0, %1" : "=a"(aB[k]) : "v"(z));
  }
  int s_cur = -1;
  float xg0[TILE], xg1[TILE];

  for (int t0 = 0; t0 < L; t0 += TILE) {  // t0 mult of 8, t0 <= 504: no x overrun
    // ---- stage x[b, t0..t0+TILE) -> fp16 LDS (256 threads, float4 each) ----
    if (tid < TILE * Ii / 4) {
      float4 xf = ((const float4*)(x + ((size_t)b * Tt + t0) * Ii))[tid];
      CV8 cv;
      cv.h[0] = (_Float16)xf.x;
      cv.h[1] = (_Float16)xf.y;
      cv.h[2] = (_Float16)xf.z;
      cv.h[3] = (_Float16)xf.w;
      ((uint2*)xs)[tid] = cv.u;
    }
    __syncthreads();  // xs visible (also h_h init before first step)

    // ---- per-tile segment ids (block-uniform) ----
    int segv[TILE];
#pragma unroll
    for (int tt = 0; tt < TILE; tt++) {
      int t = t0 + tt;
      segv[tt] = (t >= tb1) + (t >= tb2) + (t >= tb3);
    }
    const int s_lo = segv[0];
    const int tlast = (t0 + TILE - 1 < L) ? (t0 + TILE - 1) : (L - 1);
    const int s_hi = (tlast >= tb1) + (tlast >= tb2) + (tlast >= tb3);

    // ---- phase A (merged rows): xg[row][tt] = W_ih[seg(t)]@x_t + bias ----------
    for (int s = s_lo; s <= s_hi; s++) {  // <= 2 iterations
      float acc0[TILE], acc1[TILE];
#pragma unroll
      for (int tt = 0; tt < TILE; tt++) { acc0[tt] = 0.f; acc1[tt] = 0.f; }
      const uint4* wbi = wt_ih16 + ((size_t)s * 16) * G4;
#pragma unroll 2
      for (int i8 = 0; i8 < 16; i8++) {  // W_ih streamed once per tile, reused 8x
        uint4 w0 = wbi[(size_t)i8 * G4 + r0];
        uint4 w1 = wbi[(size_t)i8 * G4 + r1];
#pragma unroll
        for (int tt = 0; tt < TILE; tt++) {
          uint4 hv = xs4[tt * 16 + i8];  // wave-uniform LDS broadcast, shared rows
          acc0[tt] = dot8(w0, hv, acc0[tt]);
          acc1[tt] = dot8(w1, hv, acc1[tt]);
        }
      }
      float bias0 = b_ih[s * G4 + r0] + b_hh[s * G4 + r0];
      float bias1 = b_ih[s * G4 + r1] + b_hh[s * G4 + r1];
#pragma unroll
      for (int tt = 0; tt < TILE; tt++) {
        if (segv[tt] == s) {
          xg0[tt] = acc0[tt] + bias0;
          xg1[tt] = acc1[tt] + bias1;
        }
      }
    }

    // ---- recurrence steps (fully unrolled; all arrays statically indexed) ----
#pragma unroll
    for (int tt = 0; tt < TILE; tt++) {
      const int t = t0 + tt;
      if (t < L) {  // block-uniform
        const int s = segv[tt];
        if (s != s_cur) {  // block-uniform, <= 4 times total
          s_cur = s;
          const uint4* wb0 = wt_hh16 + (size_t)s * 32 * G4 + r0;
          const uint4* wb1 = wt_hh16 + (size_t)s * 32 * G4 + r1;
#pragma unroll
          for (int j = 0; j < 10; j++) lds_w[j * 512 + tid] = wb0[(size_t)j * G4];
#pragma unroll
          for (int j = 0; j < 9; j++)
            lds_w[(10 + j) * 512 + tid] = wb1[(size_t)j * G4];
#pragma unroll
          for (int k = 0; k < 6; k++) w0v[k] = wb0[(size_t)(10 + k) * G4];
#pragma unroll
          for (int k = 0; k < 4; k++) w1v[k] = wb1[(size_t)(9 + k) * G4];
#pragma unroll
          for (int k = 0; k < 16; k++) {  // r0 c16..31 -> AGPR
            uint4 w = wb0[(size_t)(16 + k) * G4];
            AGW4(aA[4 * k + 0], aA[4 * k + 1], aA[4 * k + 2], aA[4 * k + 3], w);
          }
#pragma unroll
          for (int k = 0; k < 19; k++) {  // r1 c13..31 -> AGPR
            uint4 w = wb1[(size_t)(13 + k) * G4];
            AGW4(aB[4 * k + 0], aB[4 * k + 1], aB[4 * k + 2], aB[4 * k + 3], w);
          }
        }
        float a0 = xg0[tt], a1 = xg1[tt];
        float a0b = 0.f, a1b = 0.f;  // even/odd chains halve dependency depth
        __syncthreads();  // B1: prev h_h visible
#pragma unroll
        for (int i8 = 0; i8 < 32; i8++) {
          uint4 hv = h4[i8];  // wave-uniform LDS broadcast
          uint4 wA, wB;
          if (i8 < 10) wA = lds_w[i8 * 512 + tid];          // conflict-free b128
          else if (i8 < 16) wA = w0v[i8 - 10];
          else AGR4(wA, aA[4 * (i8 - 16) + 0], aA[4 * (i8 - 16) + 1],
                    aA[4 * (i8 - 16) + 2], aA[4 * (i8 - 16) + 3]);
          if (i8 < 9) wB = lds_w[(10 + i8) * 512 + tid];
          else if (i8 < 13) wB = w1v[i8 - 9];
          else AGR4(wB, aB[4 * (i8 - 13) + 0], aB[4 * (i8 - 13) + 1],
                    aB[4 * (i8 - 13) + 2], aB[4 * (i8 - 13) + 3]);
          if (i8 & 1) { a0b = dot8(wA, hv, a0b); a1b = dot8(wB, hv, a1b); }
          else        { a0  = dot8(wA, hv, a0 ); a1  = dot8(wB, hv, a1 ); }
        }
        a0 += a0b;
        a1 += a1b;
        if (pr == 1) {
          f_sh[u] = 1.f / (1.f + expf(-a0));
          o_sh[u] = 1.f / (1.f + expf(-a1));
        }
        __syncthreads();  // B2: h reads done; f/o visible
        if (pr == 0) {
          float ig = 1.f / (1.f + expf(-a0));
          float gg = tanhf(a1);
          c = f_sh[u] * c + ig * gg;
          float h = o_sh[u] * tanhf(c);
          h_h[u] = (_Float16)h;
          outb[(size_t)t * Hh + u] = h;
          if (t == L - 1) lastb[u] = h;
        }
      }
    }
  }
  // zero tail t >= L (all 512 threads, coalesced float4)
  {
    const int ztotal = (Tt - L) * (Hh / 4);
    float4* zb = (float4*)(outb + (size_t)L * Hh);
    float4 z; z.x = z.y = z.z = z.w = 0.f;
    for (int i = tid; i < ztotal; i += 512) zb[i] = z;
  }
}

extern "C" void kernel_launch(void* const* d_in, const int* in_sizes, int n_in,
                              void* d_out, int out_size, void* d_ws, size_t ws_size,
                              hipStream_t stream) {
  const float* x = (const float*)d_in[0];
  const int* mask = (const int*)d_in[1];
  const float* W_ih = (const float*)d_in[2];
  const float* W_hh = (const float*)d_in[3];
  const float* b_ih = (const float*)d_in[4];
  const float* b_hh = (const float*)d_in[5];
  float* out = (float*)d_out;
  char* ws = (char*)d_ws;

  const size_t HH16_OFF = 0;
  const size_t HH16_BYTES = (size_t)Ss * 32 * G4 * 16;  // 2 MiB
  const size_t IH16_OFF = HH16_OFF + HH16_BYTES;
  const size_t IH16_BYTES = (size_t)Ss * 16 * G4 * 16;  // 1 MiB
  const size_t LEN_OFF = IH16_OFF + IH16_BYTES;

  uint4* wt_hh16 = (uint4*)(ws + HH16_OFF);
  uint4* wt_ih16 = (uint4*)(ws + IH16_OFF);
  int* len = (int*)(ws + LEN_OFF);

  k_len<<<Bb, 256, 0, stream>>>(mask, len);
  k_tr<<<768, 256, 0, stream>>>(W_ih, W_hh, wt_hh16, wt_ih16);
  k_fused<<<Bb, 512, 0, stream>>>(x, wt_hh16, wt_ih16, b_ih, b_hh, len, out);
}